// Round 5
// baseline (880.245 us; speedup 1.0000x reference)
//
#include <hip/hip_runtime.h>

#define TT  128
#define CC  256
#define VV  25
#define KK  3
#define GG  9
#define LL  9
#define NCC 60
#define CINN 3
#define TV    (TT*VV)          // 3200 (input x layout)
#define N4    4096             // padded activation columns: n = t*32+v
#define KDIM2 (CC*GG)          // 2304
#define UR    ((TT+8)*32)      // 4352 Ut2 rows: row = (t+8)*32+v
#define KSPLIT 4
#define KCH   (KDIM2/KSPLIT)   // 576

typedef __attribute__((ext_vector_type(8))) short bf16x8;
typedef __attribute__((ext_vector_type(4))) float f32x4;
typedef unsigned short us16;

__device__ __forceinline__ us16 f2bf(float f) {
    union { float f; unsigned u; } a; a.f = f;
    unsigned r = a.u + 0x7fff + ((a.u >> 16) & 1);
    return (us16)(r >> 16);
}
__device__ __forceinline__ bf16x8 ld8(const us16* p) { return *(const bf16x8*)p; }

// ---------------- merged prep kernel ----------------
// ranges: [0,N1) cvt Wg ; [N1,N1+N2) Wt transpose ; then AlT ; then bgAl

#define PN1 (LL*KK*CC*CC)       // 589824
#define PN2 (LL*CC*CC*GG)       // 5308416
#define PN3 (LL*KK*32*32)       // 9216
#define PN4 (LL*CC*32)          // 73728
#define PTOT (PN1+PN2+PN3+PN4)

__global__ void k_prep(const float* __restrict__ Wg, const float* __restrict__ Wt,
                       const float* __restrict__ A, const float* __restrict__ imp,
                       const float* __restrict__ bg,
                       us16* __restrict__ Wgb, us16* __restrict__ Wt2b,
                       us16* __restrict__ AlTb, float* __restrict__ bgAl) {
    int i = blockIdx.x * 256 + threadIdx.x;
    if (i < PN1) {
        Wgb[i] = f2bf(Wg[i]);
    } else if (i < PN1 + PN2) {
        int j = i - PN1;
        int kk = j % (CC*GG);
        int o  = (j / (CC*GG)) % CC;
        int l  = j / (CC*CC*GG);
        int g = kk >> 8, c = kk & 255;
        Wt2b[j] = f2bf(Wt[((size_t)(l*CC + o)*CC + c)*GG + g]);
    } else if (i < PN1 + PN2 + PN3) {
        int j = i - PN1 - PN2;
        int v = j & 31, w = (j >> 5) & 31;
        int lk = j >> 10, k = lk % KK, l = lk / KK;
        float val = 0.f;
        if (v < VV && w < VV)
            val = A[(k*VV+v)*VV + w] * imp[((size_t)(l*KK+k)*VV+v)*VV + w];
        AlTb[j] = f2bf(val);
    } else if (i < PTOT) {
        int j = i - PN1 - PN2 - PN3;
        int w = j & 31, c = (j >> 5) & 255, l = j >> 13;
        float s = 0.f;
        if (w < VV) {
            for (int k = 0; k < KK; k++) {
                float col = 0.f;
                for (int v = 0; v < VV; v++)
                    col += A[(k*VV+v)*VV + w] * imp[((size_t)(l*KK+k)*VV+v)*VV + w];
                s += bg[l*KK*CC + k*CC + c] * col;
            }
        }
        bgAl[j] = s;
    }
}

// ---------------- input stage: LN_in + fcn_in ----------------

__global__ __launch_bounds__(256) void k_h0(const float* __restrict__ x,
                                            const float* __restrict__ lnw,
                                            const float* __restrict__ lnb,
                                            const float* __restrict__ Win,
                                            const float* __restrict__ bin,
                                            float* __restrict__ H,
                                            us16* __restrict__ Hbt2) {
    int t = blockIdx.x, tid = threadIdx.x;
    __shared__ float sx[CINN*VV];
    __shared__ float sh[CINN*VV];
    if (tid < CINN*VV)
        sx[tid] = x[(size_t)(tid/VV)*TV + t*VV + (tid%VV)];
    __syncthreads();
    float s = 0.f, q = 0.f;
    for (int i = 0; i < CINN*VV; i++) { float v = sx[i]; s += v; q += v*v; }
    float m  = s * (1.f/75.f);
    float var = q * (1.f/75.f) - m*m;
    float rs = rsqrtf(var + 1e-5f);
    if (tid < CINN*VV)
        sh[tid] = (sx[tid]-m)*rs*lnw[tid] + lnb[tid];
    __syncthreads();
    int c = tid;
    float w0 = Win[c*3+0], w1 = Win[c*3+1], w2 = Win[c*3+2], b = bin[c];
    #pragma unroll
    for (int v = 0; v < VV; v++) {
        float acc = b + w0*sh[v] + w1*sh[VV+v] + w2*sh[2*VV+v];
        H[(size_t)c*N4 + t*32 + v] = acc;
        Hbt2[(size_t)(t*32 + v)*CC + c] = f2bf(acc);
    }
    #pragma unroll
    for (int v = VV; v < 32; v++)
        Hbt2[(size_t)(t*32 + v)*CC + c] = 0;
}

// ---------------- block reduce (sum, sumsq) ----------------

__device__ __forceinline__ void blk_reduce2(float& s, float& q, float* red) {
    #pragma unroll
    for (int off = 32; off; off >>= 1) {
        s += __shfl_down(s, off);
        q += __shfl_down(q, off);
    }
    int lane = threadIdx.x & 63, w = threadIdx.x >> 6;
    if (lane == 0) { red[w] = s; red[4+w] = q; }
    __syncthreads();
    s = red[0]+red[1]+red[2]+red[3];
    q = red[4]+red[5]+red[6]+red[7];
}

// ---------------- GEMM1: Y = Wg @ H  (768 x 4096, K=256) -> Ybt[t][c][k*32+v] ----------------

__global__ __launch_bounds__(256) void k_gemm1(const us16* __restrict__ A,
                                               const us16* __restrict__ Bt,
                                               us16* __restrict__ Ybt) {
    __shared__ us16 Yl[64*72];
    const int tid = threadIdx.x;
    const int wave = tid >> 6, lane = tid & 63, quad = lane >> 4, l16 = lane & 15;
    const int m0w = blockIdx.y * 64 + (wave & 1) * 32;
    const int n0w = blockIdx.x * 64 + (wave >> 1) * 32;
    const us16* ap = A + (size_t)(m0w + l16) * CC + quad * 8;
    const us16* bp = Bt + (size_t)(n0w + l16) * CC + quad * 8;
    f32x4 acc[2][2] = {};
    #pragma unroll
    for (int s = 0; s < 8; s++) {
        bf16x8 a0 = ld8(ap + s*32);
        bf16x8 a1 = ld8(ap + s*32 + 16*CC);
        bf16x8 b0 = ld8(bp + s*32);
        bf16x8 b1 = ld8(bp + s*32 + 16*CC);
        acc[0][0] = __builtin_amdgcn_mfma_f32_16x16x32_bf16(a0, b0, acc[0][0], 0,0,0);
        acc[0][1] = __builtin_amdgcn_mfma_f32_16x16x32_bf16(a0, b1, acc[0][1], 0,0,0);
        acc[1][0] = __builtin_amdgcn_mfma_f32_16x16x32_bf16(a1, b0, acc[1][0], 0,0,0);
        acc[1][1] = __builtin_amdgcn_mfma_f32_16x16x32_bf16(a1, b1, acc[1][1], 0,0,0);
    }
    #pragma unroll
    for (int mt = 0; mt < 2; mt++)
        #pragma unroll
        for (int nt = 0; nt < 2; nt++)
            #pragma unroll
            for (int r = 0; r < 4; r++) {
                int m_loc = (wave & 1)*32 + mt*16 + quad*4 + r;
                int n_loc = (wave >> 1)*32 + nt*16 + l16;
                Yl[m_loc*72 + n_loc] = f2bf(acc[mt][nt][r]);
            }
    __syncthreads();
    const int kidx = (blockIdx.y * 64) >> 8;
    const int c0   = (blockIdx.y * 64) & 255;
    const int t0   = blockIdx.x * 2;
    #pragma unroll
    for (int u = 0; u < 2; u++) {
        int q = tid*2 + u;
        int ch = q & 3, row = q >> 2;
        int cl = row & 63, tl = row >> 6;
        bf16x8 val = *(const bf16x8*)(Yl + cl*72 + tl*32 + ch*8);
        *(bf16x8*)(Ybt + ((size_t)((t0+tl)*CC + c0 + cl))*96 + kidx*32 + ch*8) = val;
    }
}

// ---------------- adjacency (MFMA, M=256 N=32 K=96) + LN1 + ReLU -> Ut2 ----------------

__global__ __launch_bounds__(256) void k_adj(const us16* __restrict__ Ybt,
                                             const us16* __restrict__ AlTb,
                                             const float* __restrict__ bgAl,
                                             const float* __restrict__ lnw,
                                             const float* __restrict__ lnb,
                                             us16* __restrict__ Ut2) {
    int t = blockIdx.x, tid = threadIdx.x;
    if (t >= TT) {                    // 8 history pad frames
        int tp = t - TT, c = tid;
        #pragma unroll
        for (int w = 0; w < 32; w++) {
            float u = (w < VV) ? fmaxf(lnb[c*VV + w], 0.f) : 0.f;
            Ut2[(size_t)(tp*32 + w)*CC + c] = f2bf(u);
        }
        return;
    }
    __shared__ float red[8];
    const int wave = tid >> 6, lane = tid & 63, quad = lane >> 4, l16 = lane & 15;
    bf16x8 al[2][3];
    #pragma unroll
    for (int nt = 0; nt < 2; nt++)
        #pragma unroll
        for (int s = 0; s < 3; s++)
            al[nt][s] = ld8(AlTb + (size_t)(s*32 + nt*16 + l16)*32 + quad*8);
    f32x4 z[4][2];
    #pragma unroll
    for (int mt = 0; mt < 4; mt++) { z[mt][0] = (f32x4){}; z[mt][1] = (f32x4){}; }
    #pragma unroll
    for (int mt = 0; mt < 4; mt++) {
        const us16* yp = Ybt + ((size_t)(t*CC + wave*64 + mt*16 + l16))*96 + quad*8;
        #pragma unroll
        for (int s = 0; s < 3; s++) {
            bf16x8 a = ld8(yp + s*32);
            z[mt][0] = __builtin_amdgcn_mfma_f32_16x16x32_bf16(a, al[0][s], z[mt][0], 0,0,0);
            z[mt][1] = __builtin_amdgcn_mfma_f32_16x16x32_bf16(a, al[1][s], z[mt][1], 0,0,0);
        }
    }
    float s_ = 0.f, q_ = 0.f;
    #pragma unroll
    for (int mt = 0; mt < 4; mt++)
        #pragma unroll
        for (int nt = 0; nt < 2; nt++)
            #pragma unroll
            for (int r = 0; r < 4; r++) {
                int c = wave*64 + mt*16 + quad*4 + r;
                int w = nt*16 + l16;
                float zb = z[mt][nt][r] + bgAl[c*32 + w];
                z[mt][nt][r] = zb;
                if (w < VV) { s_ += zb; q_ += zb*zb; }
            }
    blk_reduce2(s_, q_, red);
    float m = s_ * (1.f/6400.f);
    float var = q_ * (1.f/6400.f) - m*m;
    float rs = rsqrtf(var + 1e-5f);
    #pragma unroll
    for (int mt = 0; mt < 4; mt++)
        #pragma unroll
        for (int nt = 0; nt < 2; nt++) {
            int w = nt*16 + l16;
            if (w < VV) {
                int c0 = wave*64 + mt*16 + quad*4;
                ushort4 pk;
                float u0 = fmaxf((z[mt][nt][0]-m)*rs*lnw[(c0+0)*VV+w] + lnb[(c0+0)*VV+w], 0.f);
                float u1 = fmaxf((z[mt][nt][1]-m)*rs*lnw[(c0+1)*VV+w] + lnb[(c0+1)*VV+w], 0.f);
                float u2 = fmaxf((z[mt][nt][2]-m)*rs*lnw[(c0+2)*VV+w] + lnb[(c0+2)*VV+w], 0.f);
                float u3 = fmaxf((z[mt][nt][3]-m)*rs*lnw[(c0+3)*VV+w] + lnb[(c0+3)*VV+w], 0.f);
                pk.x = f2bf(u0); pk.y = f2bf(u1); pk.z = f2bf(u2); pk.w = f2bf(u3);
                *(ushort4*)(Ut2 + (size_t)((t+8)*32 + w)*CC + c0) = pk;
            }
        }
    #pragma unroll
    for (int r = VV; r < 32; r++)
        Ut2[(size_t)((t+8)*32 + r)*CC + tid] = 0;
}

// ---------------- GEMM2: partial TC = Wt2 @ Ushift, K-split x4, register-pipelined ----------------

__global__ __launch_bounds__(256) void k_gemm2(const us16* __restrict__ A,
                                               const us16* __restrict__ Ut2,
                                               float* __restrict__ TCp) {
    const int tid = threadIdx.x;
    const int wave = tid >> 6, lane = tid & 63, quad = lane >> 4, l16 = lane & 15;
    const int m0w = blockIdx.y * 64 + (wave & 1) * 32;
    const int n0w = blockIdx.x * 64 + (wave >> 1) * 32;
    const int ks = blockIdx.z;
    const int kbeg = ks * KCH, kend = kbeg + KCH;
    float* TC = TCp + (size_t)ks * CC * N4;
    const us16* ap = A + (size_t)(m0w + l16) * KDIM2 + quad * 8;
    f32x4 acc00 = {}, acc01 = {}, acc10 = {}, acc11 = {};
    bf16x8 a0, a1, b0, b1;

    auto loadAB = [&](int k0, bf16x8& x0, bf16x8& x1, bf16x8& y0, bf16x8& y1) {
        x0 = ld8(ap + k0);
        x1 = ld8(ap + k0 + 16*KDIM2);
        int g = k0 >> 8;
        const us16* bp = Ut2 + (size_t)(n0w + (8-g)*32 + l16)*CC + (k0 & 255) + quad*8;
        y0 = ld8(bp);
        y1 = ld8(bp + 16*CC);
    };
    loadAB(kbeg, a0, a1, b0, b1);
    #pragma unroll 3
    for (int k0 = kbeg + 32; k0 < kend; k0 += 32) {
        bf16x8 c0, c1, d0, d1;
        loadAB(k0, c0, c1, d0, d1);
        acc00 = __builtin_amdgcn_mfma_f32_16x16x32_bf16(a0, b0, acc00, 0,0,0);
        acc01 = __builtin_amdgcn_mfma_f32_16x16x32_bf16(a0, b1, acc01, 0,0,0);
        acc10 = __builtin_amdgcn_mfma_f32_16x16x32_bf16(a1, b0, acc10, 0,0,0);
        acc11 = __builtin_amdgcn_mfma_f32_16x16x32_bf16(a1, b1, acc11, 0,0,0);
        a0 = c0; a1 = c1; b0 = d0; b1 = d1;
    }
    acc00 = __builtin_amdgcn_mfma_f32_16x16x32_bf16(a0, b0, acc00, 0,0,0);
    acc01 = __builtin_amdgcn_mfma_f32_16x16x32_bf16(a0, b1, acc01, 0,0,0);
    acc10 = __builtin_amdgcn_mfma_f32_16x16x32_bf16(a1, b0, acc10, 0,0,0);
    acc11 = __builtin_amdgcn_mfma_f32_16x16x32_bf16(a1, b1, acc11, 0,0,0);

    const int r0 = m0w + quad*4;
    const int col = n0w + l16;
    #pragma unroll
    for (int r = 0; r < 4; r++) {
        TC[(size_t)(r0 + r)*N4 + col]           = acc00[r];
        TC[(size_t)(r0 + r)*N4 + col + 16]      = acc01[r];
        TC[(size_t)(r0 + 16 + r)*N4 + col]      = acc10[r];
        TC[(size_t)(r0 + 16 + r)*N4 + col + 16] = acc11[r];
    }
}

// ---------------- LN2 + bias + delayed residual + ReLU (sums K-split partials) ----------------

__global__ __launch_bounds__(256) void k_ln2(const float* __restrict__ TCp,
                                             const float* __restrict__ bt,
                                             const float* __restrict__ lnw,
                                             const float* __restrict__ lnb,
                                             const float* __restrict__ Hin,
                                             float* __restrict__ Hout,
                                             us16* __restrict__ Hbt2) {
    int t = blockIdx.x, tid = threadIdx.x;
    __shared__ float sv[CC*33];
    __shared__ float red[8];
    #pragma unroll
    for (int j = 0; j < 8; j++) {
        int c = j*32 + (tid >> 3);
        int v4 = (tid & 7) * 4;
        size_t base = (size_t)c*N4 + t*32 + v4;
        float4 x = *(const float4*)(TCp + base);
        #pragma unroll
        for (int s = 1; s < KSPLIT; s++) {
            float4 y = *(const float4*)(TCp + (size_t)s*CC*N4 + base);
            x.x += y.x; x.y += y.y; x.z += y.z; x.w += y.w;
        }
        sv[c*33 + v4+0] = x.x; sv[c*33 + v4+1] = x.y;
        sv[c*33 + v4+2] = x.z; sv[c*33 + v4+3] = x.w;
    }
    __syncthreads();
    int c = tid;
    float btc = bt[c];
    float vals[VV];
    float s = 0.f, q = 0.f;
    #pragma unroll
    for (int v = 0; v < VV; v++) {
        float x = sv[c*33 + v] + btc;
        vals[v] = x; s += x; q += x*x;
    }
    blk_reduce2(s, q, red);
    float m = s * (1.f/6400.f);
    float var = q * (1.f/6400.f) - m*m;
    float rs = rsqrtf(var + 1e-5f);
    #pragma unroll
    for (int v = 0; v < VV; v++) {
        float res = (t >= 4) ? Hin[(size_t)c*N4 + (t-4)*32 + v] : 0.f;
        float o = fmaxf((vals[v]-m)*rs*lnw[c*VV+v] + lnb[c*VV+v] + res, 0.f);
        Hout[(size_t)c*N4 + t*32 + v] = o;
        sv[c*33 + v] = o;
    }
    #pragma unroll
    for (int v = 0; v < VV; v++)
        Hbt2[(size_t)(t*32 + v)*CC + tid] = f2bf(sv[tid*33 + v]);
    #pragma unroll
    for (int v = VV; v < 32; v++)
        Hbt2[(size_t)(t*32 + v)*CC + tid] = 0;
}

// ---------------- pool + classifier ----------------

__global__ __launch_bounds__(256) void k_out(const float* __restrict__ H,
                                             const float* __restrict__ Wout,
                                             const float* __restrict__ bout,
                                             float* __restrict__ out) {
    int t = blockIdx.x, tid = threadIdx.x;
    __shared__ float sp[CC];
    float s = 0.f;
    for (int v = 0; v < VV; v++) s += H[(size_t)tid*N4 + t*32 + v];
    sp[tid] = s * (1.f/VV);
    __syncthreads();
    if (tid < NCC) {
        float acc = bout[tid];
        for (int c = 0; c < CC; c++) acc = fmaf(Wout[tid*CC+c], sp[c], acc);
        out[t*NCC + tid] = acc;
    }
}

// ---------------- launch ----------------

extern "C" void kernel_launch(void* const* d_in, const int* in_sizes, int n_in,
                              void* d_out, int out_size, void* d_ws, size_t ws_size,
                              hipStream_t stream) {
    const float* x    = (const float*)d_in[0];
    const float* A    = (const float*)d_in[1];
    const float* lniw = (const float*)d_in[2];
    const float* lnib = (const float*)d_in[3];
    const float* Win  = (const float*)d_in[4];
    const float* bin  = (const float*)d_in[5];
    const float* Wg   = (const float*)d_in[6];
    const float* bg   = (const float*)d_in[7];
    const float* ln1w = (const float*)d_in[8];
    const float* ln1b = (const float*)d_in[9];
    const float* Wt   = (const float*)d_in[10];
    const float* bt   = (const float*)d_in[11];
    const float* ln2w = (const float*)d_in[12];
    const float* ln2b = (const float*)d_in[13];
    const float* imp  = (const float*)d_in[14];
    const float* Wout = (const float*)d_in[15];
    const float* bout = (const float*)d_in[16];
    float* out = (float*)d_out;

    float* ws = (float*)d_ws;
    size_t off = 0;
    auto alloc = [&](size_t n) { float* p = ws + off; off += (n + 255) & ~(size_t)255; return p; };
    float* H0   = alloc((size_t)CC*N4);
    float* H1   = alloc((size_t)CC*N4);
    float* TCp  = alloc((size_t)KSPLIT*CC*N4);
    float* bgAl = alloc((size_t)LL*CC*32);
    us16* Wgb  = (us16*)alloc((size_t)LL*KK*CC*CC/2);
    us16* Wt2b = (us16*)alloc((size_t)LL*CC*KDIM2/2);
    us16* Hbt2 = (us16*)alloc((size_t)N4*CC/2);
    us16* Ut2  = (us16*)alloc((size_t)UR*CC/2);
    us16* AlTb = (us16*)alloc((size_t)LL*KK*32*32/2);
    us16* Ybt  = (us16*)alloc((size_t)TT*CC*96/2);
    (void)ws_size; (void)in_sizes; (void)n_in; (void)out_size;

    k_prep<<<(PTOT + 255)/256, 256, 0, stream>>>(Wg, Wt, A, imp, bg,
                                                 Wgb, Wt2b, AlTb, bgAl);
    k_h0<<<TT, 256, 0, stream>>>(x, lniw, lnib, Win, bin, H0, Hbt2);

    float* Hin = H0; float* Hout = H1;
    for (int l = 0; l < LL; l++) {
        k_gemm1<<<dim3(N4/64, (KK*CC)/64), 256, 0, stream>>>(
            Wgb + (size_t)l*KK*CC*CC, Hbt2, Ybt);
        k_adj<<<TT + 8, 256, 0, stream>>>(
            Ybt, AlTb + (size_t)l*KK*32*32, bgAl + (size_t)l*CC*32,
            ln1w + l*CC*VV, ln1b + l*CC*VV, Ut2);
        k_gemm2<<<dim3(N4/64, CC/64, KSPLIT), 256, 0, stream>>>(
            Wt2b + (size_t)l*CC*KDIM2, Ut2, TCp);
        k_ln2<<<TT, 256, 0, stream>>>(
            TCp, bt + l*CC, ln2w + l*CC*VV, ln2b + l*CC*VV, Hin, Hout, Hbt2);
        float* tmp = Hin; Hin = Hout; Hout = tmp;
    }
    k_out<<<TT, 256, 0, stream>>>(Hin, Wout, bout, out);
}